// Round 10
// baseline (169.028 us; speedup 1.0000x reference)
//
#include <hip/hip_runtime.h>
#include <math.h>

// InfoNCE loss, K=3, SKIP=1, NEG=64
// z,c: (64,256,14,14) f32; Wk: (3,256,256) f32; neg_idx_k: (rows_k*64,) i32
// rows_k = 10752, 9856, 8960. row = (h*14+w)*64 + b.
//
// Pipeline (4 launches): prep (casts+transposes+zero), proj (LDS-staged bf16
// MFMA GEMM -> ztwk fp8, L2-resident), loss (barrier-free: each WAVE owns a
// private LDS slab, DMA-gathers its row's 65 neighbors, vmcnt-waits, fp8
// MFMA + softmax — 8 independent streams/CU), reduce.

typedef short bf16x8 __attribute__((ext_vector_type(8)));
typedef float f32x4 __attribute__((ext_vector_type(4)));

static __device__ __forceinline__ unsigned short f2bf(float f) {
    union { float f; unsigned int u; } x; x.f = f;
    unsigned int r = x.u + 0x7fffu + ((x.u >> 16) & 1u);   // RNE
    return (unsigned short)(r >> 16);
}

// float -> OCP e4m3fn (RNE, saturate to 448, subnormals handled)
static __device__ __forceinline__ unsigned char f2e4m3(float f) {
    union { float f; unsigned int u; } x; x.f = f;
    unsigned int s = (x.u >> 24) & 0x80u;
    float af = fabsf(f);
    if (af > 448.f) af = 448.f;
    x.f = af;
    unsigned int u = x.u;
    int e = (int)(u >> 23) - 127;
    unsigned int out;
    if (af == 0.f) {
        out = 0u;
    } else if (e < -6) {
        int mq = (int)rintf(af * 512.f);          // multiples of 2^-9
        out = (mq >= 8) ? 0x08u : (unsigned int)mq;
    } else {
        unsigned int r = u + 0x7FFFFu + ((u >> 20) & 1u);  // RNE, drop 20 bits
        int e2 = (int)(r >> 23) - 127;
        if (e2 > 8) out = 0x7Eu;                  // 448
        else out = (unsigned int)(((e2 + 7) << 3) | ((r >> 20) & 7u));
    }
    return (unsigned char)(s | out);
}

// async global->LDS DMA: per-lane global addr, dest = uniform base + lane*4
static __device__ __forceinline__ void gload_lds4(const void* g, void* l) {
    __builtin_amdgcn_global_load_lds(
        (const __attribute__((address_space(1))) void*)g,
        (__attribute__((address_space(3))) void*)l, 4, 0, 0);
}

// prep: blocks [0,768): Wk->bf16 (block0 also zeroes out[0]);
// [768,1792): z -> zt bf16 transposed; [1792,2816): c -> ct8 fp8 transposed.
__global__ __launch_bounds__(256)
void prep_kernel(const float* __restrict__ z, const float* __restrict__ c,
                 const float* __restrict__ Wk,
                 unsigned short* __restrict__ zt, unsigned char* __restrict__ ct8,
                 unsigned short* __restrict__ wkb, float* __restrict__ out) {
    __shared__ float tile[16][201];
    const int tid = threadIdx.x;
    int x = blockIdx.x;
    if (x < 768) {
        int i = x * 256 + tid;
        wkb[i] = f2bf(Wk[i]);
        if (x == 0 && tid == 0) out[0] = 0.f;
        return;
    }
    const bool isz = x < 1792;
    const int local = isz ? (x - 768) : (x - 1792);
    const float* src = isz ? z : c;
    const int b  = local & 63;
    const int c0 = (local >> 6) << 4;
    for (int i = tid; i < 16 * 196; i += 256) {
        int cc = i / 196;
        int hw = i - cc * 196;
        tile[cc][hw] = src[(size_t)((b << 8) + c0 + cc) * 196 + hw];
    }
    __syncthreads();
    if (isz) {
        for (int i = tid; i < 196 * 16; i += 256) {
            int hw = i >> 4, cc = i & 15;
            zt[(size_t)((hw << 6) + b) * 256 + c0 + cc] = f2bf(tile[cc][hw]);
        }
    } else {
        for (int i = tid; i < 196 * 16; i += 256) {
            int hw = i >> 4, cc = i & 15;
            ct8[(size_t)((hw << 6) + b) * 256 + c0 + cc] = f2e4m3(tile[cc][hw]);
        }
    }
}

// proj: ztwk8[k][row][o] = fp8(sum_c zt[zrow][c] * wk[k][o][c])
// Tile M=64 x N=32, grid (462, 8). Coalesced b128 stage into padded LDS
// (row stride 544 B), frags from LDS, fp8 epilogue via LDS. (Verified R8.)
#define PSTR 544
__global__ __launch_bounds__(256)
void proj_mfma_kernel(const unsigned short* __restrict__ zt,
                      const unsigned short* __restrict__ wkb,
                      unsigned char* __restrict__ ztwk) {
    __shared__ __align__(16) unsigned char smem[(64 + 32) * PSTR];  // 52224 B
    unsigned char* smA = smem;
    unsigned char* smB = smem + 64 * PSTR;

    int x = blockIdx.x;
    int k, hw;
    if (x < 168)      { k = 0; hw = x; }
    else if (x < 322) { k = 1; hw = x - 168; }
    else              { k = 2; hw = x - 322; }
    const int o0 = blockIdx.y << 5;
    const int row0  = hw << 6;
    const int zrow0 = row0 + (((k + 2) * 14) << 6);    // h' = h + (k_idx+2)
    unsigned char* zo = ztwk + (size_t)k * 10752 * 256;

    const int tid = threadIdx.x;
    const unsigned char* zsrc = (const unsigned char*)(zt + (size_t)zrow0 * 256);
    const unsigned char* bsrc = (const unsigned char*)(wkb + ((size_t)k << 16) + o0 * 256);

    #pragma unroll
    for (int i = 0; i < 8; ++i) {          // A: 32 KB contiguous
        int sb = ((i << 8) + tid) << 4;
        int r = sb >> 9, off = sb & 511;
        *(int4*)(smA + r * PSTR + off) = *(const int4*)(zsrc + sb);
    }
    #pragma unroll
    for (int i = 0; i < 4; ++i) {          // B: 16 KB contiguous
        int sb = ((i << 8) + tid) << 4;
        int r = sb >> 9, off = sb & 511;
        *(int4*)(smB + r * PSTR + off) = *(const int4*)(bsrc + sb);
    }
    __syncthreads();

    const int wv = tid >> 6, lane = tid & 63;
    const int m = lane & 15, kq = lane >> 4;
    f32x4 acc[2] = {};
    const unsigned short* aP  = (const unsigned short*)(smA + (size_t)((wv << 4) + m) * PSTR) + (kq << 3);
    const unsigned short* bP0 = (const unsigned short*)(smB + (size_t)m * PSTR) + (kq << 3);
    const unsigned short* bP1 = (const unsigned short*)(smB + (size_t)(16 + m) * PSTR) + (kq << 3);
    #pragma unroll
    for (int kk = 0; kk < 256; kk += 32) {
        bf16x8 af = *(const bf16x8*)(aP  + kk);
        bf16x8 b0 = *(const bf16x8*)(bP0 + kk);
        bf16x8 b1 = *(const bf16x8*)(bP1 + kk);
        acc[0] = __builtin_amdgcn_mfma_f32_16x16x32_bf16(af, b0, acc[0], 0, 0, 0);
        acc[1] = __builtin_amdgcn_mfma_f32_16x16x32_bf16(af, b1, acc[1], 0, 0, 0);
    }
    __syncthreads();
    unsigned char* cs = smA;               // [64 rows][40 B]
    #pragma unroll
    for (int nt = 0; nt < 2; ++nt)
        #pragma unroll
        for (int r = 0; r < 4; ++r)
            cs[(size_t)((wv << 4) + (kq << 2) + r) * 40 + (nt << 4) + m] =
                f2e4m3(acc[nt][r]);
    __syncthreads();
    {
        int r = tid >> 2, off = (tid & 3) << 3;
        unsigned long long v = *(const unsigned long long*)(cs + (size_t)r * 40 + off);
        *(unsigned long long*)(zo + (size_t)(row0 + r) * 256 + o0 + off) = v;
    }
}

// loss: barrier-free. Grid 1848 x 128; each of the 3696 WAVES independently
// processes 8 consecutive rows of one k-segment (all segment sizes are
// divisible by 8, so no wave straddles segments). Per task: 66 global->LDS
// DMAs into the wave's private slab, explicit s_waitcnt vmcnt(0) (compiler
// does not track DMA->LDS deps), fp8 MFMA over 5 M-tiles (slot-64 clamp for
// pads), single-wave softmax (verified R5/R8). lgkmcnt(0) fence before slab
// reuse guards ds_read-vs-DMA-write overlap. No __syncthreads anywhere.
#define ROWB 272
#define SLABSZ (65 * ROWB + 272)   // 17952 B per wave (ctx row at 65*ROWB)
__global__ __launch_bounds__(128)
void loss_mfma_kernel(const unsigned char* __restrict__ ct8,
                      const unsigned char* __restrict__ ztwk8,
                      const int* __restrict__ n0, const int* __restrict__ n1,
                      const int* __restrict__ n2, float* __restrict__ rowloss) {
    __shared__ __align__(16) unsigned char lds[2][SLABSZ];   // 35904 B
    const int tid = threadIdx.x;
    const int wv = tid >> 6, lane = tid & 63;
    const int m = lane & 15, kq = lane >> 4;
    unsigned char* sl  = lds[wv];
    unsigned char* ctx = sl + 65 * ROWB;

    const int W = (blockIdx.x << 1) + wv;   // global wave id, 0..3695
    const int base = W << 3;                // first global row index (8 per wave)
    int k; const int* nb; int segbase;
    if (base < 10752)      { k = 0; nb = n0; segbase = 0; }
    else if (base < 20608) { k = 1; nb = n1; segbase = 10752; }
    else                   { k = 2; nb = n2; segbase = 20608; }
    const int row0 = base - segbase;
    const unsigned char* flat8 = ztwk8 + (size_t)k * 10752 * 256;
    const float wkf = (k == 0) ? (1.f / (3.f * 10752.f))
                    : (k == 1) ? (1.f / (3.f * 9856.f))
                               : (1.f / (3.f * 8960.f));

    int soff[5];
    #pragma unroll
    for (int mt = 0; mt < 5; ++mt) {
        int slot = (mt << 4) + m;
        if (slot > 64) slot = 64;           // pad slots duplicate 64 (excluded)
        soff[mt] = slot * ROWB + (kq << 3);
    }

    int myidx = nb[((size_t)row0 << 6) + lane];

    for (int t = 0; t < 8; ++t) {
        const int row = row0 + t;
        // slab reuse fence: all prior ds_reads complete before DMA overwrites
        asm volatile("s_waitcnt lgkmcnt(0)" ::: "memory");
        gload_lds4(flat8 + (size_t)row * 256 + (lane << 2), sl);       // slot 0
        gload_lds4(ct8 + (size_t)row * 256 + (lane << 2), ctx);
        #pragma unroll
        for (int j = 1; j <= 64; ++j) {
            int idx = __builtin_amdgcn_readlane(myidx, j - 1);
            gload_lds4(flat8 + (size_t)idx * 256 + (lane << 2), sl + j * ROWB);
        }
        asm volatile("s_waitcnt vmcnt(0)" ::: "memory");   // DMA drain (per-wave)
        if (t + 1 < 8)
            myidx = nb[((size_t)(row + 1) << 6) + lane];   // prefetch next idx

        f32x4 acc[5] = {};
        const unsigned char* cp = ctx + (kq << 3);
        #pragma unroll
        for (int kk = 0; kk < 8; ++kk) {
            long long bfrag = *(const long long*)(cp + (kk << 5));
            #pragma unroll
            for (int mt = 0; mt < 5; ++mt) {
                long long af = *(const long long*)(sl + soff[mt] + (kk << 5));
                acc[mt] = __builtin_amdgcn_mfma_f32_16x16x32_fp8_fp8(
                    af, bfrag, acc[mt], 0, 0, 0);
            }
        }

        // softmax over slots 0..64 (slot = mt*16 + kq*4 + r)
        float m_l = -1e30f;
        #pragma unroll
        for (int mt = 0; mt < 4; ++mt)
            #pragma unroll
            for (int r = 0; r < 4; ++r) m_l = fmaxf(m_l, acc[mt][r]);
        if (kq == 0) m_l = fmaxf(m_l, acc[4][0]);
        m_l = fmaxf(m_l, __shfl_xor(m_l, 16));
        m_l = fmaxf(m_l, __shfl_xor(m_l, 32));
        float s_l = 0.f;
        #pragma unroll
        for (int mt = 0; mt < 4; ++mt)
            #pragma unroll
            for (int r = 0; r < 4; ++r) s_l += __expf(acc[mt][r] - m_l);
        if (kq == 0) s_l += __expf(acc[4][0] - m_l);
        s_l += __shfl_xor(s_l, 16);
        s_l += __shfl_xor(s_l, 32);
        if (lane == 0) {                    // lane 0 holds slot 0 (acc[0][0])
            float p0 = __expf(acc[0][0] - m_l) / s_l;
            rowloss[base + t] = -logf(p0 + 1e-11f) * wkf;
        }
    }
}

// Sum rowloss[0..29568) -> out[0] (out zeroed in prep)
__global__ __launch_bounds__(256)
void reduce_kernel(const float* __restrict__ rl, float* __restrict__ out) {
    float s = 0.f;
    const int stride = gridDim.x * blockDim.x;
    for (int i = blockIdx.x * blockDim.x + threadIdx.x; i < 29568; i += stride)
        s += rl[i];
    #pragma unroll
    for (int off = 32; off >= 1; off >>= 1) s += __shfl_xor(s, off);
    if ((threadIdx.x & 63) == 0) atomicAdd(out, s);
}

extern "C" void kernel_launch(void* const* d_in, const int* in_sizes, int n_in,
                              void* d_out, int out_size, void* d_ws, size_t ws_size,
                              hipStream_t stream) {
    const float* z  = (const float*)d_in[0];
    const float* c  = (const float*)d_in[1];
    const float* Wk = (const float*)d_in[2];
    const int* negs[3] = {(const int*)d_in[3], (const int*)d_in[4], (const int*)d_in[5]};
    float* out = (float*)d_out;

    // workspace: zt bf16 6.4MB | wkb bf16 384KB | ct8 fp8 3.2MB |
    // ztwk8 fp8 [3][10752][256] 8.26MB | rowloss f32 118KB
    char* p = (char*)d_ws;
    unsigned short* zt      = (unsigned short*)p;   p += (size_t)196 * 64 * 256 * 2;
    unsigned short* wkb     = (unsigned short*)p;   p += (size_t)3 * 65536 * 2;
    unsigned char*  ct8     = (unsigned char*)p;    p += (size_t)196 * 64 * 256;
    unsigned char*  ztwk8   = (unsigned char*)p;    p += (size_t)3 * 10752 * 256;
    float*          rowloss = (float*)p;

    prep_kernel<<<2816, 256, 0, stream>>>(z, c, Wk, zt, ct8, wkb, out);
    proj_mfma_kernel<<<dim3(462, 8), 256, 0, stream>>>(zt, wkb, ztwk8);
    loss_mfma_kernel<<<1848, 128, 0, stream>>>(ct8, ztwk8, negs[0], negs[1],
                                               negs[2], rowloss);
    reduce_kernel<<<32, 256, 0, stream>>>(rowloss, out);
}

// Round 11
// 162.775 us; speedup vs baseline: 1.0384x; 1.0384x over previous
//
#include <hip/hip_runtime.h>
#include <math.h>

// InfoNCE loss, K=3, SKIP=1, NEG=64
// z,c: (64,256,14,14) f32; Wk: (3,256,256) f32; neg_idx_k: (rows_k*64,) i32
// rows_k = 10752, 9856, 8960. row = (h*14+w)*64 + b.
//
// Pipeline (4 launches): prep, proj (LDS-staged bf16 MFMA -> ztwk fp8,
// L2-resident), loss (per-wave GROUP-PIPELINED gather: 4 x 16-row groups +
// head per task, 3 rotating LDS buffers, two groups always in flight,
// s_waitcnt vmcnt(32) — never a full drain), reduce.

typedef short bf16x8 __attribute__((ext_vector_type(8)));
typedef float f32x4 __attribute__((ext_vector_type(4)));

static __device__ __forceinline__ unsigned short f2bf(float f) {
    union { float f; unsigned int u; } x; x.f = f;
    unsigned int r = x.u + 0x7fffu + ((x.u >> 16) & 1u);   // RNE
    return (unsigned short)(r >> 16);
}

// float -> OCP e4m3fn (RNE, saturate to 448, subnormals handled)
static __device__ __forceinline__ unsigned char f2e4m3(float f) {
    union { float f; unsigned int u; } x; x.f = f;
    unsigned int s = (x.u >> 24) & 0x80u;
    float af = fabsf(f);
    if (af > 448.f) af = 448.f;
    x.f = af;
    unsigned int u = x.u;
    int e = (int)(u >> 23) - 127;
    unsigned int out;
    if (af == 0.f) {
        out = 0u;
    } else if (e < -6) {
        int mq = (int)rintf(af * 512.f);
        out = (mq >= 8) ? 0x08u : (unsigned int)mq;
    } else {
        unsigned int r = u + 0x7FFFFu + ((u >> 20) & 1u);
        int e2 = (int)(r >> 23) - 127;
        if (e2 > 8) out = 0x7Eu;
        else out = (unsigned int)(((e2 + 7) << 3) | ((r >> 20) & 7u));
    }
    return (unsigned char)(s | out);
}

// async global->LDS DMA: per-lane global addr, dest = uniform base + lane*4
static __device__ __forceinline__ void gload_lds4(const void* g, void* l) {
    __builtin_amdgcn_global_load_lds(
        (const __attribute__((address_space(1))) void*)g,
        (__attribute__((address_space(3))) void*)l, 4, 0, 0);
}

static __device__ __forceinline__ void wait_vmcnt_32() {
    asm volatile("s_waitcnt vmcnt(32)" ::: "memory");
}
static __device__ __forceinline__ void wait_vmcnt_16() {
    asm volatile("s_waitcnt vmcnt(16)" ::: "memory");
}
static __device__ __forceinline__ void wait_vmcnt_0() {
    asm volatile("s_waitcnt vmcnt(0)" ::: "memory");
}
static __device__ __forceinline__ void fence_lgkm0() {
    asm volatile("s_waitcnt lgkmcnt(0)" ::: "memory");
}

// prep: blocks [0,768): Wk->bf16 (block0 zeroes out[0]);
// [768,1792): z -> zt bf16 transposed; [1792,2816): c -> ct8 fp8 transposed.
__global__ __launch_bounds__(256)
void prep_kernel(const float* __restrict__ z, const float* __restrict__ c,
                 const float* __restrict__ Wk,
                 unsigned short* __restrict__ zt, unsigned char* __restrict__ ct8,
                 unsigned short* __restrict__ wkb, float* __restrict__ out) {
    __shared__ float tile[16][201];
    const int tid = threadIdx.x;
    int x = blockIdx.x;
    if (x < 768) {
        int i = x * 256 + tid;
        wkb[i] = f2bf(Wk[i]);
        if (x == 0 && tid == 0) out[0] = 0.f;
        return;
    }
    const bool isz = x < 1792;
    const int local = isz ? (x - 768) : (x - 1792);
    const float* src = isz ? z : c;
    const int b  = local & 63;
    const int c0 = (local >> 6) << 4;
    for (int i = tid; i < 16 * 196; i += 256) {
        int cc = i / 196;
        int hw = i - cc * 196;
        tile[cc][hw] = src[(size_t)((b << 8) + c0 + cc) * 196 + hw];
    }
    __syncthreads();
    if (isz) {
        for (int i = tid; i < 196 * 16; i += 256) {
            int hw = i >> 4, cc = i & 15;
            zt[(size_t)((hw << 6) + b) * 256 + c0 + cc] = f2bf(tile[cc][hw]);
        }
    } else {
        for (int i = tid; i < 196 * 16; i += 256) {
            int hw = i >> 4, cc = i & 15;
            ct8[(size_t)((hw << 6) + b) * 256 + c0 + cc] = f2e4m3(tile[cc][hw]);
        }
    }
}

// proj: ztwk8[k][row][o] = fp8(sum_c zt[zrow][c] * wk[k][o][c])  (verified R8)
#define PSTR 544
__global__ __launch_bounds__(256)
void proj_mfma_kernel(const unsigned short* __restrict__ zt,
                      const unsigned short* __restrict__ wkb,
                      unsigned char* __restrict__ ztwk) {
    __shared__ __align__(16) unsigned char smem[(64 + 32) * PSTR];
    unsigned char* smA = smem;
    unsigned char* smB = smem + 64 * PSTR;

    int x = blockIdx.x;
    int k, hw;
    if (x < 168)      { k = 0; hw = x; }
    else if (x < 322) { k = 1; hw = x - 168; }
    else              { k = 2; hw = x - 322; }
    const int o0 = blockIdx.y << 5;
    const int row0  = hw << 6;
    const int zrow0 = row0 + (((k + 2) * 14) << 6);
    unsigned char* zo = ztwk + (size_t)k * 10752 * 256;

    const int tid = threadIdx.x;
    const unsigned char* zsrc = (const unsigned char*)(zt + (size_t)zrow0 * 256);
    const unsigned char* bsrc = (const unsigned char*)(wkb + ((size_t)k << 16) + o0 * 256);

    #pragma unroll
    for (int i = 0; i < 8; ++i) {
        int sb = ((i << 8) + tid) << 4;
        int r = sb >> 9, off = sb & 511;
        *(int4*)(smA + r * PSTR + off) = *(const int4*)(zsrc + sb);
    }
    #pragma unroll
    for (int i = 0; i < 4; ++i) {
        int sb = ((i << 8) + tid) << 4;
        int r = sb >> 9, off = sb & 511;
        *(int4*)(smB + r * PSTR + off) = *(const int4*)(bsrc + sb);
    }
    __syncthreads();

    const int wv = tid >> 6, lane = tid & 63;
    const int m = lane & 15, kq = lane >> 4;
    f32x4 acc[2] = {};
    const unsigned short* aP  = (const unsigned short*)(smA + (size_t)((wv << 4) + m) * PSTR) + (kq << 3);
    const unsigned short* bP0 = (const unsigned short*)(smB + (size_t)m * PSTR) + (kq << 3);
    const unsigned short* bP1 = (const unsigned short*)(smB + (size_t)(16 + m) * PSTR) + (kq << 3);
    #pragma unroll
    for (int kk = 0; kk < 256; kk += 32) {
        bf16x8 af = *(const bf16x8*)(aP  + kk);
        bf16x8 b0 = *(const bf16x8*)(bP0 + kk);
        bf16x8 b1 = *(const bf16x8*)(bP1 + kk);
        acc[0] = __builtin_amdgcn_mfma_f32_16x16x32_bf16(af, b0, acc[0], 0, 0, 0);
        acc[1] = __builtin_amdgcn_mfma_f32_16x16x32_bf16(af, b1, acc[1], 0, 0, 0);
    }
    __syncthreads();
    unsigned char* cs = smA;
    #pragma unroll
    for (int nt = 0; nt < 2; ++nt)
        #pragma unroll
        for (int r = 0; r < 4; ++r)
            cs[(size_t)((wv << 4) + (kq << 2) + r) * 40 + (nt << 4) + m] =
                f2e4m3(acc[nt][r]);
    __syncthreads();
    {
        int r = tid >> 2, off = (tid & 3) << 3;
        unsigned long long v = *(const unsigned long long*)(cs + (size_t)r * 40 + off);
        *(unsigned long long*)(zo + (size_t)(row0 + r) * 256 + o0 + off) = v;
    }
}

// loss: one 64-thread block (1 wave) per 8 consecutive rows of a k-segment.
// Per task: 4 groups of 16 rows (slots g*16..g*16+15; slot0 = self) + head
// (ctx row + neg63 row). Issue-ahead of 2 groups into 3 rotating buffers;
// s_waitcnt vmcnt(32) before consuming a group guarantees (in-order VMEM
// retirement) that group + its head are complete while the next two groups
// stay in flight. ctx read once per task into 8 b64 regs. Softmax over
// slots 0..64 (acc[4][0] at kq==0 = slot 64), as verified R5/R8.
#define GROWB 272
#define GBUF (16 * GROWB)
__global__ __launch_bounds__(64)
void loss_mfma_kernel(const unsigned char* __restrict__ ct8,
                      const unsigned char* __restrict__ ztwk8,
                      const int* __restrict__ n0, const int* __restrict__ n1,
                      const int* __restrict__ n2, float* __restrict__ rowloss) {
    __shared__ __align__(16) unsigned char buf[3][GBUF];        // 13056 B
    __shared__ __align__(16) unsigned char head[2][2 * GROWB];  // 1088 B
    const int lane = threadIdx.x;
    const int m = lane & 15, kq = lane >> 4;

    const int base = blockIdx.x << 3;       // first global row (8 per wave)
    int k; const int* nb; int segbase;
    if (base < 10752)      { k = 0; nb = n0; segbase = 0; }
    else if (base < 20608) { k = 1; nb = n1; segbase = 10752; }
    else                   { k = 2; nb = n2; segbase = 20608; }
    const int row0 = base - segbase;
    const unsigned char* flat8 = ztwk8 + (size_t)k * 10752 * 256;
    const float wkf = (k == 0) ? (1.f / (3.f * 10752.f))
                    : (k == 1) ? (1.f / (3.f * 9856.f))
                               : (1.f / (3.f * 8960.f));

    // neg indices for all 8 tasks (one vector load each; compiler-tracked)
    int idxv[8];
    #pragma unroll
    for (int t = 0; t < 8; ++t)
        idxv[t] = nb[((size_t)(row0 + t) << 6) + lane];

    const unsigned int laneoff = lane << 2;

    // prologue: head(0), groups q=0 (t0,g0) and q=1 (t0,g1)
    {
        gload_lds4(ct8 + (size_t)row0 * 256 + laneoff, &head[0][0]);
        int g4i = __builtin_amdgcn_readlane(idxv[0], 63);
        gload_lds4(flat8 + (size_t)g4i * 256 + laneoff, &head[0][GROWB]);
        #pragma unroll
        for (int r = 0; r < 16; ++r) {
            int ridx = (r == 0) ? row0 : __builtin_amdgcn_readlane(idxv[0], r - 1);
            gload_lds4(flat8 + (size_t)ridx * 256 + laneoff, &buf[0][r * GROWB]);
        }
        #pragma unroll
        for (int r = 0; r < 16; ++r) {
            int ridx = __builtin_amdgcn_readlane(idxv[0], 15 + r);
            gload_lds4(flat8 + (size_t)ridx * 256 + laneoff, &buf[1][r * GROWB]);
        }
    }

    long long ctxr[8];
    f32x4 acc[5];

    #pragma unroll
    for (int t = 0; t < 8; ++t) {
        #pragma unroll
        for (int g = 0; g < 5; ++g) {
            if (g < 4) {
                const int q = (t << 2) + g;
                if (q + 2 <= 31) {                     // issue group q+2
                    const int q2 = q + 2;
                    const int t2 = q2 >> 2, g2 = q2 & 3;
                    fence_lgkm0();                     // buffer-reuse fence
                    if (g2 == 0) {                     // head for task t2
                        int hrow = row0 + t2;
                        gload_lds4(ct8 + (size_t)hrow * 256 + laneoff,
                                   &head[t2 & 1][0]);
                        int g4i = __builtin_amdgcn_readlane(idxv[t2], 63);
                        gload_lds4(flat8 + (size_t)g4i * 256 + laneoff,
                                   &head[t2 & 1][GROWB]);
                    }
                    const int bi2 = q2 % 3;
                    #pragma unroll
                    for (int r = 0; r < 16; ++r) {
                        int slot = (g2 << 4) + r;
                        int ridx = (slot == 0) ? (row0 + t2)
                                 : __builtin_amdgcn_readlane(idxv[t2], slot - 1);
                        gload_lds4(flat8 + (size_t)ridx * 256 + laneoff,
                                   &buf[bi2][r * GROWB]);
                    }
                }
                if (q <= 29)      wait_vmcnt_32();     // group q (+head) done
                else if (q == 30) wait_vmcnt_16();
                else              wait_vmcnt_0();

                if (g == 0) {                          // ctx -> regs, reset acc
                    #pragma unroll
                    for (int kk = 0; kk < 8; ++kk)
                        ctxr[kk] = *(const long long*)(
                            &head[t & 1][(kq << 3) + (kk << 5)]);
                    #pragma unroll
                    for (int i = 0; i < 5; ++i)
                        acc[i] = (f32x4){0.f, 0.f, 0.f, 0.f};
                }
                const int bi = q % 3;
                #pragma unroll
                for (int kk = 0; kk < 8; ++kk) {
                    long long af = *(const long long*)(
                        &buf[bi][m * GROWB + (kq << 3) + (kk << 5)]);
                    acc[g] = __builtin_amdgcn_mfma_f32_16x16x32_fp8_fp8(
                        af, ctxr[kk], acc[g], 0, 0, 0);
                }
            } else {
                // g == 4: neg63 row lives in head (ensured done at (t,0))
                #pragma unroll
                for (int kk = 0; kk < 8; ++kk) {
                    long long af = *(const long long*)(
                        &head[t & 1][GROWB + (kq << 3) + (kk << 5)]);
                    acc[4] = __builtin_amdgcn_mfma_f32_16x16x32_fp8_fp8(
                        af, ctxr[kk], acc[4], 0, 0, 0);
                }
                // softmax over slots 0..64 (slot = g*16 + kq*4 + r)
                float m_l = -1e30f;
                #pragma unroll
                for (int mt = 0; mt < 4; ++mt)
                    #pragma unroll
                    for (int r = 0; r < 4; ++r) m_l = fmaxf(m_l, acc[mt][r]);
                if (kq == 0) m_l = fmaxf(m_l, acc[4][0]);
                m_l = fmaxf(m_l, __shfl_xor(m_l, 16));
                m_l = fmaxf(m_l, __shfl_xor(m_l, 32));
                float s_l = 0.f;
                #pragma unroll
                for (int mt = 0; mt < 4; ++mt)
                    #pragma unroll
                    for (int r = 0; r < 4; ++r) s_l += __expf(acc[mt][r] - m_l);
                if (kq == 0) s_l += __expf(acc[4][0] - m_l);
                s_l += __shfl_xor(s_l, 16);
                s_l += __shfl_xor(s_l, 32);
                if (lane == 0) {                       // lane 0 holds slot 0
                    float p0 = __expf(acc[0][0] - m_l) / s_l;
                    rowloss[base + t] = -logf(p0 + 1e-11f) * wkf;
                }
            }
        }
    }
}

// Sum rowloss[0..29568) -> out[0] (out zeroed in prep)
__global__ __launch_bounds__(256)
void reduce_kernel(const float* __restrict__ rl, float* __restrict__ out) {
    float s = 0.f;
    const int stride = gridDim.x * blockDim.x;
    for (int i = blockIdx.x * blockDim.x + threadIdx.x; i < 29568; i += stride)
        s += rl[i];
    #pragma unroll
    for (int off = 32; off >= 1; off >>= 1) s += __shfl_xor(s, off);
    if ((threadIdx.x & 63) == 0) atomicAdd(out, s);
}

extern "C" void kernel_launch(void* const* d_in, const int* in_sizes, int n_in,
                              void* d_out, int out_size, void* d_ws, size_t ws_size,
                              hipStream_t stream) {
    const float* z  = (const float*)d_in[0];
    const float* c  = (const float*)d_in[1];
    const float* Wk = (const float*)d_in[2];
    const int* negs[3] = {(const int*)d_in[3], (const int*)d_in[4], (const int*)d_in[5]};
    float* out = (float*)d_out;

    char* p = (char*)d_ws;
    unsigned short* zt      = (unsigned short*)p;   p += (size_t)196 * 64 * 256 * 2;
    unsigned short* wkb     = (unsigned short*)p;   p += (size_t)3 * 65536 * 2;
    unsigned char*  ct8     = (unsigned char*)p;    p += (size_t)196 * 64 * 256;
    unsigned char*  ztwk8   = (unsigned char*)p;    p += (size_t)3 * 10752 * 256;
    float*          rowloss = (float*)p;

    prep_kernel<<<2816, 256, 0, stream>>>(z, c, Wk, zt, ct8, wkb, out);
    proj_mfma_kernel<<<dim3(462, 8), 256, 0, stream>>>(zt, wkb, ztwk8);
    loss_mfma_kernel<<<3696, 64, 0, stream>>>(ct8, ztwk8, negs[0], negs[1],
                                              negs[2], rowloss);
    reduce_kernel<<<32, 256, 0, stream>>>(rowloss, out);
}

// Round 12
// 155.163 us; speedup vs baseline: 1.0894x; 1.0491x over previous
//
#include <hip/hip_runtime.h>
#include <math.h>

// InfoNCE loss, K=3, SKIP=1, NEG=64
// z,c: (64,256,14,14) f32; Wk: (3,256,256) f32; neg_idx_k: (rows_k*64,) i32
// rows_k = 10752, 9856, 8960. row = (h*14+w)*64 + b.
//
// Pipeline (4 launches): prep (casts+transposes+zero), proj (LDS-staged bf16
// MFMA GEMM -> ztwk fp8, L2-resident; grid o-fast for A-tile L2 reuse),
// loss (R8 structure — TA-floor ~51us: 2-wave block per row, DMA gather +
// one barrier + fp8 MFMA + cross-wave softmax), reduce.

typedef short bf16x8 __attribute__((ext_vector_type(8)));
typedef float f32x4 __attribute__((ext_vector_type(4)));

static __device__ __forceinline__ unsigned short f2bf(float f) {
    union { float f; unsigned int u; } x; x.f = f;
    unsigned int r = x.u + 0x7fffu + ((x.u >> 16) & 1u);   // RNE
    return (unsigned short)(r >> 16);
}

// float -> OCP e4m3fn (RNE, saturate to 448, subnormals handled)
static __device__ __forceinline__ unsigned char f2e4m3(float f) {
    union { float f; unsigned int u; } x; x.f = f;
    unsigned int s = (x.u >> 24) & 0x80u;
    float af = fabsf(f);
    if (af > 448.f) af = 448.f;
    x.f = af;
    unsigned int u = x.u;
    int e = (int)(u >> 23) - 127;
    unsigned int out;
    if (af == 0.f) {
        out = 0u;
    } else if (e < -6) {
        int mq = (int)rintf(af * 512.f);          // multiples of 2^-9
        out = (mq >= 8) ? 0x08u : (unsigned int)mq;
    } else {
        unsigned int r = u + 0x7FFFFu + ((u >> 20) & 1u);  // RNE, drop 20 bits
        int e2 = (int)(r >> 23) - 127;
        if (e2 > 8) out = 0x7Eu;                  // 448
        else out = (unsigned int)(((e2 + 7) << 3) | ((r >> 20) & 7u));
    }
    return (unsigned char)(s | out);
}

// async global->LDS DMA: per-lane global addr, dest = uniform base + lane*4
static __device__ __forceinline__ void gload_lds4(const void* g, void* l) {
    __builtin_amdgcn_global_load_lds(
        (const __attribute__((address_space(1))) void*)g,
        (__attribute__((address_space(3))) void*)l, 4, 0, 0);
}

// prep: blocks [0,768): Wk->bf16 (block0 also zeroes out[0]);
// [768,1792): z -> zt bf16 transposed; [1792,2816): c -> ct8 fp8 transposed.
__global__ __launch_bounds__(256)
void prep_kernel(const float* __restrict__ z, const float* __restrict__ c,
                 const float* __restrict__ Wk,
                 unsigned short* __restrict__ zt, unsigned char* __restrict__ ct8,
                 unsigned short* __restrict__ wkb, float* __restrict__ out) {
    __shared__ float tile[16][201];
    const int tid = threadIdx.x;
    int x = blockIdx.x;
    if (x < 768) {
        int i = x * 256 + tid;
        wkb[i] = f2bf(Wk[i]);
        if (x == 0 && tid == 0) out[0] = 0.f;
        return;
    }
    const bool isz = x < 1792;
    const int local = isz ? (x - 768) : (x - 1792);
    const float* src = isz ? z : c;
    const int b  = local & 63;
    const int c0 = (local >> 6) << 4;
    for (int i = tid; i < 16 * 196; i += 256) {
        int cc = i / 196;
        int hw = i - cc * 196;
        tile[cc][hw] = src[(size_t)((b << 8) + c0 + cc) * 196 + hw];
    }
    __syncthreads();
    if (isz) {
        for (int i = tid; i < 196 * 16; i += 256) {
            int hw = i >> 4, cc = i & 15;
            zt[(size_t)((hw << 6) + b) * 256 + c0 + cc] = f2bf(tile[cc][hw]);
        }
    } else {
        for (int i = tid; i < 196 * 16; i += 256) {
            int hw = i >> 4, cc = i & 15;
            ct8[(size_t)((hw << 6) + b) * 256 + c0 + cc] = f2e4m3(tile[cc][hw]);
        }
    }
}

// proj: ztwk8[k][row][o] = fp8(sum_c zt[zrow][c] * wk[k][o][c])
// Grid (8, 462): o-tile is blockIdx.x (FAST) so the 8 o-tiles of one hw-tile
// dispatch consecutively -> A tile stays L2-hot (zt streamed ~once from HBM,
// not 8x). Tile M=64 x N=32. PSTR 528: dword stride 132 == 4 (mod 32) ->
// free 2-way frag-read banking (544's ==8 gave 4-way).
#define PSTR 528
__global__ __launch_bounds__(256)
void proj_mfma_kernel(const unsigned short* __restrict__ zt,
                      const unsigned short* __restrict__ wkb,
                      unsigned char* __restrict__ ztwk) {
    __shared__ __align__(16) unsigned char smem[(64 + 32) * PSTR];  // 50688 B
    unsigned char* smA = smem;
    unsigned char* smB = smem + 64 * PSTR;

    int x = blockIdx.y;
    int k, hw;
    if (x < 168)      { k = 0; hw = x; }
    else if (x < 322) { k = 1; hw = x - 168; }
    else              { k = 2; hw = x - 322; }
    const int o0 = blockIdx.x << 5;                    // 32 outs per block
    const int row0  = hw << 6;
    const int zrow0 = row0 + (((k + 2) * 14) << 6);    // h' = h + (k_idx+2)
    unsigned char* zo = ztwk + (size_t)k * 10752 * 256;

    const int tid = threadIdx.x;
    const unsigned char* zsrc = (const unsigned char*)(zt + (size_t)zrow0 * 256);
    const unsigned char* bsrc = (const unsigned char*)(wkb + ((size_t)k << 16) + o0 * 256);

    #pragma unroll
    for (int i = 0; i < 8; ++i) {          // A: 32 KB contiguous
        int sb = ((i << 8) + tid) << 4;
        int r = sb >> 9, off = sb & 511;
        *(int4*)(smA + r * PSTR + off) = *(const int4*)(zsrc + sb);
    }
    #pragma unroll
    for (int i = 0; i < 4; ++i) {          // B: 16 KB contiguous
        int sb = ((i << 8) + tid) << 4;
        int r = sb >> 9, off = sb & 511;
        *(int4*)(smB + r * PSTR + off) = *(const int4*)(bsrc + sb);
    }
    __syncthreads();

    const int wv = tid >> 6, lane = tid & 63;
    const int m = lane & 15, kq = lane >> 4;
    f32x4 acc[2] = {};
    const unsigned short* aP  = (const unsigned short*)(smA + (size_t)((wv << 4) + m) * PSTR) + (kq << 3);
    const unsigned short* bP0 = (const unsigned short*)(smB + (size_t)m * PSTR) + (kq << 3);
    const unsigned short* bP1 = (const unsigned short*)(smB + (size_t)(16 + m) * PSTR) + (kq << 3);
    #pragma unroll
    for (int kk = 0; kk < 256; kk += 32) {
        bf16x8 af = *(const bf16x8*)(aP  + kk);
        bf16x8 b0 = *(const bf16x8*)(bP0 + kk);
        bf16x8 b1 = *(const bf16x8*)(bP1 + kk);
        acc[0] = __builtin_amdgcn_mfma_f32_16x16x32_bf16(af, b0, acc[0], 0, 0, 0);
        acc[1] = __builtin_amdgcn_mfma_f32_16x16x32_bf16(af, b1, acc[1], 0, 0, 0);
    }
    __syncthreads();
    unsigned char* cs = smA;               // [64 rows][40 B]
    #pragma unroll
    for (int nt = 0; nt < 2; ++nt)
        #pragma unroll
        for (int r = 0; r < 4; ++r)
            cs[(size_t)((wv << 4) + (kq << 2) + r) * 40 + (nt << 4) + m] =
                f2e4m3(acc[nt][r]);
    __syncthreads();
    {
        int r = tid >> 2, off = (tid & 3) << 3;
        unsigned long long v = *(const unsigned long long*)(cs + (size_t)r * 40 + off);
        *(unsigned long long*)(zo + (size_t)(row0 + r) * 256 + o0 + off) = v;
    }
}

// loss (R8-verbatim, TA-floor ~51us): one block (2 waves) per row. Wave0:
// DMA rows 0..32 + MFMA mt 0..2; wave1: DMA rows 33..64 + ctx + MFMA mt 3..4.
// Slots: 0 main, 1..64 negs, 65..79 pad (clamped). Cross-wave softmax.
#define ROWB 272
__global__ __launch_bounds__(128, 4)
void loss_mfma_kernel(const unsigned char* __restrict__ ct8,
                      const unsigned char* __restrict__ ztwk8,
                      const int* __restrict__ n0, const int* __restrict__ n1,
                      const int* __restrict__ n2, float* __restrict__ rowloss) {
    __shared__ __align__(16) unsigned char slab[65 * ROWB];   // 17680 B
    __shared__ __align__(16) unsigned char ctx_s[256];
    __shared__ float sred[2][2];
    const int tid = threadIdx.x;
    const int wv = tid >> 6, lane = tid & 63;
    const int m = lane & 15, kq = lane >> 4;

    int x = blockIdx.x;
    int k; const int* nb_base;
    if (x < 10752)      { k = 0; nb_base = n0; }
    else if (x < 20608) { k = 1; nb_base = n1; x -= 10752; }
    else                { k = 2; nb_base = n2; x -= 20608; }
    const int row = x;
    const unsigned char* flat8 = ztwk8 + (size_t)k * 10752 * 256;
    const float wk = (k == 0) ? (1.f / (3.f * 10752.f))
                   : (k == 1) ? (1.f / (3.f * 9856.f))
                              : (1.f / (3.f * 8960.f));
    const int rbase = (k == 0) ? 0 : (k == 1) ? 10752 : 20608;

    const int myidx = nb_base[((size_t)row << 6) + lane];

    if (wv == 0) {
        gload_lds4(flat8 + (size_t)row * 256 + (lane << 2), slab);          // j=0
        #pragma unroll
        for (int j = 1; j <= 32; ++j) {
            int idx = __builtin_amdgcn_readlane(myidx, j - 1);
            gload_lds4(flat8 + (size_t)idx * 256 + (lane << 2), slab + j * ROWB);
        }
    } else {
        gload_lds4(ct8 + (size_t)row * 256 + (lane << 2), ctx_s);
        #pragma unroll
        for (int j = 33; j <= 64; ++j) {
            int idx = __builtin_amdgcn_readlane(myidx, j - 1);
            gload_lds4(flat8 + (size_t)idx * 256 + (lane << 2), slab + j * ROWB);
        }
    }
    __syncthreads();   // drains vmcnt (DMA) for the whole block

    f32x4 acc[3] = {};
    const int mt0 = (wv == 0) ? 0 : 3;
    int soff[3];
    #pragma unroll
    for (int t = 0; t < 3; ++t) {
        int slot = ((mt0 + t) << 4) + m;
        if (slot > 64) slot = 64;
        soff[t] = slot * ROWB + (kq << 3);
    }
    const unsigned char* cp = ctx_s + (kq << 3);
    #pragma unroll
    for (int kk = 0; kk < 8; ++kk) {
        long long bfrag = *(const long long*)(cp + (kk << 5));
        #pragma unroll
        for (int t = 0; t < 3; ++t) {
            if (t < 2 || wv == 0) {
                long long af = *(const long long*)(slab + soff[t] + (kk << 5));
                acc[t] = __builtin_amdgcn_mfma_f32_16x16x32_fp8_fp8(af, bfrag, acc[t], 0, 0, 0);
            }
        }
    }

    float m_l = -1e30f;
    if (wv == 0) {
        #pragma unroll
        for (int t = 0; t < 3; ++t)
            #pragma unroll
            for (int r = 0; r < 4; ++r) m_l = fmaxf(m_l, acc[t][r]);
    } else {
        #pragma unroll
        for (int r = 0; r < 4; ++r) m_l = fmaxf(m_l, acc[0][r]);   // mt=3
        if (kq == 0) m_l = fmaxf(m_l, acc[1][0]);                  // slot 64
    }
    m_l = fmaxf(m_l, __shfl_xor(m_l, 16));
    m_l = fmaxf(m_l, __shfl_xor(m_l, 32));

    float s_l = 0.f;
    if (wv == 0) {
        #pragma unroll
        for (int t = 0; t < 3; ++t)
            #pragma unroll
            for (int r = 0; r < 4; ++r) s_l += __expf(acc[t][r] - m_l);
    } else {
        #pragma unroll
        for (int r = 0; r < 4; ++r) s_l += __expf(acc[0][r] - m_l);
        if (kq == 0) s_l += __expf(acc[1][0] - m_l);
    }
    s_l += __shfl_xor(s_l, 16);
    s_l += __shfl_xor(s_l, 32);

    float main_l = acc[0][0];   // valid at wv0 lane0 (slot 0)
    if (lane == 0) { sred[wv][0] = m_l; sred[wv][1] = s_l; }
    __syncthreads();
    if (tid == 0) {
        float m0 = sred[0][0], s0 = sred[0][1];
        float m1 = sred[1][0], s1 = sred[1][1];
        float mg = fmaxf(m0, m1);
        float sg = s0 * __expf(m0 - mg) + s1 * __expf(m1 - mg);
        float p0 = __expf(main_l - mg) / sg;
        rowloss[rbase + row] = -logf(p0 + 1e-11f) * wk;
    }
}

// Sum rowloss[0..29568) -> out[0] (out zeroed in prep)
__global__ __launch_bounds__(256)
void reduce_kernel(const float* __restrict__ rl, float* __restrict__ out) {
    float s = 0.f;
    const int stride = gridDim.x * blockDim.x;
    for (int i = blockIdx.x * blockDim.x + threadIdx.x; i < 29568; i += stride)
        s += rl[i];
    #pragma unroll
    for (int off = 32; off >= 1; off >>= 1) s += __shfl_xor(s, off);
    if ((threadIdx.x & 63) == 0) atomicAdd(out, s);
}

extern "C" void kernel_launch(void* const* d_in, const int* in_sizes, int n_in,
                              void* d_out, int out_size, void* d_ws, size_t ws_size,
                              hipStream_t stream) {
    const float* z  = (const float*)d_in[0];
    const float* c  = (const float*)d_in[1];
    const float* Wk = (const float*)d_in[2];
    const int* negs[3] = {(const int*)d_in[3], (const int*)d_in[4], (const int*)d_in[5]};
    float* out = (float*)d_out;

    char* p = (char*)d_ws;
    unsigned short* zt      = (unsigned short*)p;   p += (size_t)196 * 64 * 256 * 2;
    unsigned short* wkb     = (unsigned short*)p;   p += (size_t)3 * 65536 * 2;
    unsigned char*  ct8     = (unsigned char*)p;    p += (size_t)196 * 64 * 256;
    unsigned char*  ztwk8   = (unsigned char*)p;    p += (size_t)3 * 10752 * 256;
    float*          rowloss = (float*)p;

    prep_kernel<<<2816, 256, 0, stream>>>(z, c, Wk, zt, ct8, wkb, out);
    proj_mfma_kernel<<<dim3(8, 462), 256, 0, stream>>>(zt, wkb, ztwk8);
    loss_mfma_kernel<<<29568, 128, 0, stream>>>(ct8, ztwk8, negs[0], negs[1],
                                                negs[2], rowloss);
    reduce_kernel<<<32, 256, 0, stream>>>(rowloss, out);
}